// Round 14
// baseline (2972.174 us; speedup 1.0000x reference)
//
#include <hip/hip_runtime.h>
#include <hip/hip_bf16.h>
#include <cstdint>

// ---------------------------------------------------------------------------
// 2-layer LSTM (B=512, T=128, F=64, H=1024) + dense sigmoid head.
// R17: R16 (2872us — T5 setprio confirmed −5.3%, session best) + B-before-A
// load order in loadS. Mechanism: the mh-wave pair of each kp-quarter loads
// IDENTICAL B (weight) addresses every kc-stage; issuing the 8 B loads
// first clusters the duplicate addresses at stage boundaries where the
// pair is most closely phased -> L1/MSHR in-flight merge serves both from
// one L2-port transaction (attacks the per-CU byte-delivery term that R9
// proved large: −25% bytes -> −8.5% time). Pure issue-order change: no
// arithmetic delta, no register delta.
// Session ledger (falsified): R9 traffic −25%->−8.5%; R10 2xTLP->−4.8%;
// R11 persistent grid.sync −4.2x; R12 nontemporal +40%; R13 c-coalesce
// neutral; R14 lockstep +13.6% (0.4us/drain-barrier); R15 pairwise global
// handoff −3.3x (fences destroy L2 weight residency). Confirmed: T5
// setprio −5.3% (R16). Structure forced: weights n-sharded, h all-to-all
// per step, launch boundary = cheapest global sync.
// Step internals: 8 waves, mh=w&1 (64-row half), kp=w>>1 (K quarter);
// per-wave tile 64m x 32u x 4 gates (384 B/MFMA); 2-round LDS butterfly
// (128 KB, 3 barriers); zero-LDS GEMM loads from L2 in granule layout
// (1 KB = 16 rows x 32 k, lane-major). Grid 256 x 512thr = 1 block/CU;
// roles on XCD bits. Unified VGPR+AGPR ~252/256 at 2 waves/SIMD.
// ---------------------------------------------------------------------------

typedef __attribute__((ext_vector_type(8))) _Float16 half8;
typedef __attribute__((ext_vector_type(4))) float    float4v;

__device__ __forceinline__ float sigf(float x) { return 1.0f / (1.0f + __expf(-x)); }
__device__ __forceinline__ float tanhfast(float x) { return 2.0f * sigf(2.0f * x) - 1.0f; }

static constexpr size_t HPS = 32ull * 32 * 512;   // packed h slot (elems)

struct FragSet {          // one kc stage for one wave (48 VGPR)
    half8 A[4];           // [msub]
    half8 B[4][2];        // [gate][nf]
};

// ---------------------------------------------------------------------------
// Launch s (0..128): role 0 blocks run layer1 step t=s (skip s==128),
// role 1 blocks run layer2 step t=s-1 (skip s==0).
// b = blockIdx.x (0..255): role=(b>>3)&1, tile=((b>>4)<<3)|(b&7) in 0..127.
// tile: m-strip = tile>>5 (4 strips of 128 rows), n-strip = tile&31.
// XCD = b%8 tracks n-strip low bits for both roles -> fixed L2 weight slice.
// Wave w (0..7): mh=w&1, kp=w>>1. Wave covers 64 rows x all 32 units
// (both nf halves) over its K quarter. Reduction partners: w^2 (nf-half
// exchange), then w^4 (ms-pair exchange).
// ---------------------------------------------------------------------------
__global__ __launch_bounds__(512, 2) void fused_step(
    int s,
    const _Float16* __restrict__ xp,   // packed x: ((t*32+mG)*2+kc)*512
    const _Float16* __restrict__ P1,   // packed layer1 weights, KCB=34
    const _Float16* __restrict__ P2,   // packed layer2 weights, KCB=64
    const float* __restrict__ b1, float* __restrict__ c1, _Float16* __restrict__ h1p,
    const float* __restrict__ b2, float* __restrict__ c2, _Float16* __restrict__ h2p)
{
    const int b    = blockIdx.x;
    const int role = (b >> 3) & 1;
    const int tile = ((b >> 4) << 3) | (b & 7);    // 0..127

    const _Float16 *As0, *As1, *Pk;
    const float* bias; float* cs; _Float16* hop;
    int KC0, KCB, KCT;                 // A seg-0 len, B granule stride, total kc
    if (role == 0) {                   // ---- layer 1, step t = s ----
        const int t = s; if (t >= 128) return;
        As0 = xp + (size_t)t * 32768;  KC0 = 2;     // x granules, stride 2/mG
        As1 = h1p + (size_t)(t & 1) * HPS;          // h1(t-1), stride 32/mG
        Pk = P1; KCB = 34; KCT = 34;
        bias = b1; cs = c1;
        hop = h1p + (size_t)(1 - (t & 1)) * HPS;
    } else {                           // ---- layer 2, step t = s-1 ----
        const int t = s - 1; if (t < 0) return;
        As0 = h1p + (size_t)(1 - (t & 1)) * HPS; KC0 = 32;  // h1(t)
        As1 = h2p + (size_t)(t & 1) * HPS;                  // h2(t-1)
        Pk = P2; KCB = 64; KCT = 64;
        bias = b2; cs = c2;
        hop = h2p + (size_t)(1 - (t & 1)) * HPS;
    }

    const int tid = threadIdx.x;
    const int w   = tid >> 6;          // 0..7
    const int l   = tid & 63;
    const int q   = l >> 4;
    const int c16 = l & 15;
    const int mh  = w & 1;             // 64-row half
    const int kp  = w >> 1;            // K quarter (0..3)

    const int m0  = (tile >> 5) * 128;
    const int n0  = (tile & 31) * 32;
    const int mG0 = (m0 >> 4) + mh * 4;    // wave's first A granule (of 4)

    const size_t l8 = (size_t)l * 8;

    const _Float16* bp[4][2];          // per-(gate, nf-half) packed-B granule base
#pragma unroll
    for (int g = 0; g < 4; ++g)
#pragma unroll
        for (int nf = 0; nf < 2; ++nf)
            bp[g][nf] = Pk + ((size_t)(g * 64 + (n0 >> 4) + nf) * KCB) * 512 + l8;

    float4v acc[4][4][2] = {};         // [gate][msub][nf] = 32 frags (128 AGPR)

    auto loadS = [&](int kc, FragSet& S) {
        // B FIRST: mh-pair issues identical B addresses -> cluster them at
        // the stage boundary for L1/MSHR in-flight merge (one L2-port txn).
#pragma unroll
        for (int g = 0; g < 4; ++g)
#pragma unroll
            for (int nf = 0; nf < 2; ++nf)
                S.B[g][nf] = *(const half8*)(bp[g][nf] + (size_t)kc * 512);
        const _Float16* ab; size_t astr;
        if (kc < KC0) { ab = As0 + (size_t)kc * 512;         astr = (size_t)KC0 * 512; }
        else          { ab = As1 + (size_t)(kc - KC0) * 512; astr = 32ull * 512; }
        ab += (size_t)mG0 * astr + l8;
#pragma unroll
        for (int ms = 0; ms < 4; ++ms)
            S.A[ms] = *(const half8*)(ab + (size_t)ms * astr);
    };
    auto computeS = [&](const FragSet& S) {
        __builtin_amdgcn_s_setprio(1);             // T5: favor MFMA wave
#pragma unroll
        for (int g = 0; g < 4; ++g)
#pragma unroll
            for (int ms = 0; ms < 4; ++ms)
#pragma unroll
                for (int nf = 0; nf < 2; ++nf)
                    acc[g][ms][nf] = __builtin_amdgcn_mfma_f32_16x16x32_f16(
                        S.A[ms], S.B[g][nf], acc[g][ms][nf], 0, 0, 0);
        __builtin_amdgcn_s_setprio(0);
    };

    // ---- K loop over this wave's quarter (TLP hides load latency) ----
    const int base = KCT >> 2;                 // 8 (l1) / 16 (l2)
    const int rem  = KCT & 3;                  // 2 (l1) / 0 (l2)
    const int len  = base + (kp < rem ? 1 : 0);
    const int kcS  = kp * base + (kp < rem ? kp : rem);

    FragSet S;
#pragma unroll 2
    for (int kc = kcS; kc < kcS + len; ++kc) {
        loadS(kc, S);
        computeS(S);
    }

    // ---- 2-round cross-wave K reduction via 128 KB LDS ----
    __shared__ float4v red[8][16][64];         // [writer wave][frag][lane]
    // Round 1: exchange nf halves with partner w^2 (kp bit0 flip).
    if ((kp & 1) == 0) {
#pragma unroll
        for (int g = 0; g < 4; ++g)
#pragma unroll
            for (int ms = 0; ms < 4; ++ms)
                red[w][g * 4 + ms][l] = acc[g][ms][1];
    } else {
#pragma unroll
        for (int g = 0; g < 4; ++g)
#pragma unroll
            for (int ms = 0; ms < 4; ++ms)
                red[w][g * 4 + ms][l] = acc[g][ms][0];
    }
    __syncthreads();
    float4v acc1[4][4];                // owned nf, summed over K half
    if ((kp & 1) == 0) {
#pragma unroll
        for (int g = 0; g < 4; ++g)
#pragma unroll
            for (int ms = 0; ms < 4; ++ms)
                acc1[g][ms] = acc[g][ms][0] + red[w ^ 2][g * 4 + ms][l];
    } else {
#pragma unroll
        for (int g = 0; g < 4; ++g)
#pragma unroll
            for (int ms = 0; ms < 4; ++ms)
                acc1[g][ms] = acc[g][ms][1] + red[w ^ 2][g * 4 + ms][l];
    }
    __syncthreads();                   // WAR: buffer reused in round 2
    // Round 2: exchange ms pairs with partner w^4 (kp bit1 flip).
    if ((kp >> 1) == 0) {
#pragma unroll
        for (int g = 0; g < 4; ++g)
#pragma unroll
            for (int j = 0; j < 2; ++j)
                red[w][g * 2 + j][l] = acc1[g][2 + j];
    } else {
#pragma unroll
        for (int g = 0; g < 4; ++g)
#pragma unroll
            for (int j = 0; j < 2; ++j)
                red[w][g * 2 + j][l] = acc1[g][j];
    }
    __syncthreads();
    float4v out[4][2];                 // full sums for owned (nf, ms-pair)
    if ((kp >> 1) == 0) {
#pragma unroll
        for (int g = 0; g < 4; ++g)
#pragma unroll
            for (int j = 0; j < 2; ++j)
                out[g][j] = acc1[g][j] + red[w ^ 4][g * 2 + j][l];
    } else {
#pragma unroll
        for (int g = 0; g < 4; ++g)
#pragma unroll
            for (int j = 0; j < 2; ++j)
                out[g][j] = acc1[g][2 + j] + red[w ^ 4][g * 2 + j][l];
    }

    // ---- fused gate epilogue; h written in A-granule layout ----
    // Wave owns rows [m0+mh*64+own_msp*32, +32) x units [n0+own_nf*16, +16).
    const int own_nf  = kp & 1;
    const int own_msp = kp >> 1;
    const int ng = n0 + own_nf * 16 + c16;
    const float bi  = bias[ng];
    const float bff = bias[1024 + ng];
    const float bg  = bias[2048 + ng];
    const float bo  = bias[3072 + ng];
    const int kcH   = n0 >> 5;
    const int laneW = (own_nf * 2 + (c16 >> 3)) << 4;
    const int jW    = c16 & 7;
#pragma unroll
    for (int j = 0; j < 2; ++j) {
        const int msg = own_msp * 2 + j;
        const int mG  = mG0 + msg;
        _Float16* hg = hop + ((size_t)(mG * 32 + kcH)) * 512 + (size_t)laneW * 8 + jW;
#pragma unroll
        for (int i = 0; i < 4; ++i) {
            const int m = m0 + mh * 64 + msg * 16 + q * 4 + i;
            const float zi = out[0][j][i] + bi;
            const float zf = out[1][j][i] + bff;
            const float zg = out[2][j][i] + bg;
            const float zo = out[3][j][i] + bo;
            const float ig = sigf(zi);
            const float fg = sigf(zf);
            const float gg = tanhfast(zg);
            const float og = sigf(zo);
            const size_t cidx = (size_t)m * 1024 + ng;
            const float cc = fg * cs[cidx] + ig * gg;
            cs[cidx] = cc;
            hg[(q * 4 + i) * 8] = (_Float16)(og * tanhfast(cc));
        }
    }
}

// ---------------------------------------------------------------------------
// Pack [W (KA,4096) | U (K-KA,4096)] fp32 row-major into B-fragment granules.
// ---------------------------------------------------------------------------
__global__ void pack_weights(const float* __restrict__ W, const float* __restrict__ U,
                             int KA, int KC, _Float16* __restrict__ out)
{
    const size_t e = (size_t)blockIdx.x * blockDim.x + threadIdx.x;
    const size_t total = (size_t)256 * KC * 512;
    if (e >= total) return;
    const int j    = (int)(e & 7);
    const int lane = (int)((e >> 3) & 63);
    const size_t g = e >> 9;
    const int kc  = (int)(g % KC);
    const int ntG = (int)(g / KC);
    const int col = ntG * 16 + (lane & 15);
    const int k   = kc * 32 + (lane >> 4) * 8 + j;
    const float v = (k < KA) ? W[(size_t)k * 4096 + col]
                             : U[(size_t)(k - KA) * 4096 + col];
    out[e] = (_Float16)v;
}

// ---------------------------------------------------------------------------
// Pack x (B=512, T=128, F=64) fp32 into per-timestep A-granules.
// ---------------------------------------------------------------------------
__global__ void pack_x(const float* __restrict__ x, _Float16* __restrict__ xp)
{
    const int e = blockIdx.x * blockDim.x + threadIdx.x;
    if (e >= 512 * 128 * 64) return;
    const int j  = e & 7;
    const int l  = (e >> 3) & 63;
    const int g  = e >> 9;
    const int kc = g & 1;
    const int tm = g >> 1;
    const int mG = tm & 31;
    const int t  = tm >> 5;
    const int m  = mG * 16 + (l & 15);
    const int f  = kc * 32 + (l >> 4) * 8 + j;
    xp[e] = (_Float16)x[((size_t)m * 128 + t) * 64 + f];
}

// ---------------------------------------------------------------------------
// Dense head on packed h2: out[m] = sigmoid(h2[m,:].Wd + bd).
// ---------------------------------------------------------------------------
__global__ __launch_bounds__(64) void dense_head(const _Float16* __restrict__ h2p,
                                                 const float* __restrict__ Wd,
                                                 const float* __restrict__ bd,
                                                 float* __restrict__ out)
{
    const int mG = blockIdx.x;
    const int l  = threadIdx.x;
    float s = 0.0f;
    for (int kc = 0; kc < 32; ++kc) {
        half8 f = *(const half8*)(h2p + ((size_t)(mG * 32 + kc)) * 512 + (size_t)l * 8);
        const int kb = kc * 32 + (l >> 4) * 8;
#pragma unroll
        for (int j = 0; j < 8; ++j) s += (float)f[j] * Wd[kb + j];
    }
    s += __shfl_xor(s, 16);
    s += __shfl_xor(s, 32);
    if (l < 16) out[mG * 16 + l] = 1.0f / (1.0f + __expf(-(s + bd[0])));
}

// ---------------------------------------------------------------------------

extern "C" void kernel_launch(void* const* d_in, const int* in_sizes, int n_in,
                              void* d_out, int out_size, void* d_ws, size_t ws_size,
                              hipStream_t stream)
{
    const float* x  = (const float*)d_in[0];
    const float* W1 = (const float*)d_in[1];
    const float* U1 = (const float*)d_in[2];
    const float* b1 = (const float*)d_in[3];
    const float* W2 = (const float*)d_in[4];
    const float* U2 = (const float*)d_in[5];
    const float* b2 = (const float*)d_in[6];
    const float* Wd = (const float*)d_in[7];
    const float* bd = (const float*)d_in[8];
    float* out = (float*)d_out;

    char* ws = (char*)d_ws;
    size_t off = 0;
    auto alloc = [&](size_t bytes) {
        char* p = ws + off;
        off = (off + bytes + 255) & ~(size_t)255;
        return p;
    };
    _Float16* xp  = (_Float16*)alloc(512ull * 128 * 64 * 2);  // packed x
    _Float16* P1  = (_Float16*)alloc(256ull * 34 * 512 * 2);  // packed layer1 W|U
    _Float16* P2  = (_Float16*)alloc(256ull * 64 * 512 * 2);  // packed layer2 W|U
    _Float16* h1p = (_Float16*)alloc(2ull * HPS * 2);         // packed h1 ping-pong
    _Float16* h2p = (_Float16*)alloc(2ull * HPS * 2);         // packed h2 ping-pong
    float*    c1  = (float*)alloc(512ull * 1024 * 4);
    float*    c2  = (float*)alloc(512ull * 1024 * 4);

    // zero initial state (ws is re-poisoned to 0xAA before every launch)
    hipMemsetAsync(c1, 0, 512ull * 1024 * 4, stream);
    hipMemsetAsync(c2, 0, 512ull * 1024 * 4, stream);
    hipMemsetAsync(h1p, 0, HPS * 2, stream);   // slot 0 (read at t=0)
    hipMemsetAsync(h2p, 0, HPS * 2, stream);   // slot 0

    pack_x<<<(512 * 128 * 64 + 255) / 256, 256, 0, stream>>>(x, xp);
    pack_weights<<<(256 * 34 * 512 + 255) / 256, 256, 0, stream>>>(W1, U1, 64, 34, P1);
    pack_weights<<<(256 * 64 * 512 + 255) / 256, 256, 0, stream>>>(W2, U2, 1024, 64, P2);

    // 129 pipelined launches: launch s does layer1(s) + layer2(s-1)
    for (int s = 0; s <= 128; ++s) {
        fused_step<<<256, 512, 0, stream>>>(s, xp, P1, P2,
                                            b1, c1, h1p, b2, c2, h2p);
    }
    // h2(127) lands in slot 0
    dense_head<<<32, 64, 0, stream>>>(h2p, Wd, bd, out);
}

// Round 15
// 2824.245 us; speedup vs baseline: 1.0524x; 1.0524x over previous
//
#include <hip/hip_runtime.h>
#include <hip/hip_bf16.h>
#include <cstdint>

// ---------------------------------------------------------------------------
// 2-layer LSTM (B=512, T=128, F=64, H=1024) + dense sigmoid head.
// R18 = R16 exact (2872us, session best). R17's B-before-A load reorder
// was falsified (+3.5%: serializing the A-dep chain behind 8 B-loads cost
// more than MSHR merge saved — hipcc's original interleave wins; same
// lesson as m131/m141: source-order nudges vs compiler scheduling mostly
// subtract). Session ledger: R9 traffic −25%->−8.5%; R10 2xTLP->−4.8%
// (3034); R11 persistent grid.sync −4.2x; R12 nontemporal +40%; R13
// c-coalesce neutral; R14 lockstep +13.6%; R15 pairwise handoff −3.3x;
// R16 T5 setprio −5.3% (2872, CONFIRMED); R17 load-reorder +3.5%.
// Structure forced: weights n-sharded (per-block streaming >100us/step),
// h all-to-all per step, launch boundary = cheapest global sync.
// T5 rationale: 8 waves run the whole K-loop barrier-free at staggered
// phases (attn-like regime, m191 +4-7%), not barrier-lockstep (m190 null).
// Step internals: 8 waves, mh=w&1 (64-row half), kp=w>>1 (K quarter);
// per-wave tile 64m x 32u x 4 gates (384 B/MFMA); 2-round LDS butterfly
// (128 KB, 3 barriers); zero-LDS GEMM loads from L2 in granule layout
// (1 KB = 16 rows x 32 k, lane-major). Grid 256 x 512thr = 1 block/CU;
// roles on XCD bits. Unified VGPR+AGPR ~252/256 at 2 waves/SIMD.
// ---------------------------------------------------------------------------

typedef __attribute__((ext_vector_type(8))) _Float16 half8;
typedef __attribute__((ext_vector_type(4))) float    float4v;

__device__ __forceinline__ float sigf(float x) { return 1.0f / (1.0f + __expf(-x)); }
__device__ __forceinline__ float tanhfast(float x) { return 2.0f * sigf(2.0f * x) - 1.0f; }

static constexpr size_t HPS = 32ull * 32 * 512;   // packed h slot (elems)

struct FragSet {          // one kc stage for one wave (48 VGPR)
    half8 A[4];           // [msub]
    half8 B[4][2];        // [gate][nf]
};

// ---------------------------------------------------------------------------
// Launch s (0..128): role 0 blocks run layer1 step t=s (skip s==128),
// role 1 blocks run layer2 step t=s-1 (skip s==0).
// b = blockIdx.x (0..255): role=(b>>3)&1, tile=((b>>4)<<3)|(b&7) in 0..127.
// tile: m-strip = tile>>5 (4 strips of 128 rows), n-strip = tile&31.
// XCD = b%8 tracks n-strip low bits for both roles -> fixed L2 weight slice.
// Wave w (0..7): mh=w&1, kp=w>>1. Wave covers 64 rows x all 32 units
// (both nf halves) over its K quarter. Reduction partners: w^2 (nf-half
// exchange), then w^4 (ms-pair exchange).
// ---------------------------------------------------------------------------
__global__ __launch_bounds__(512, 2) void fused_step(
    int s,
    const _Float16* __restrict__ xp,   // packed x: ((t*32+mG)*2+kc)*512
    const _Float16* __restrict__ P1,   // packed layer1 weights, KCB=34
    const _Float16* __restrict__ P2,   // packed layer2 weights, KCB=64
    const float* __restrict__ b1, float* __restrict__ c1, _Float16* __restrict__ h1p,
    const float* __restrict__ b2, float* __restrict__ c2, _Float16* __restrict__ h2p)
{
    const int b    = blockIdx.x;
    const int role = (b >> 3) & 1;
    const int tile = ((b >> 4) << 3) | (b & 7);    // 0..127

    const _Float16 *As0, *As1, *Pk;
    const float* bias; float* cs; _Float16* hop;
    int KC0, KCB, KCT;                 // A seg-0 len, B granule stride, total kc
    if (role == 0) {                   // ---- layer 1, step t = s ----
        const int t = s; if (t >= 128) return;
        As0 = xp + (size_t)t * 32768;  KC0 = 2;     // x granules, stride 2/mG
        As1 = h1p + (size_t)(t & 1) * HPS;          // h1(t-1), stride 32/mG
        Pk = P1; KCB = 34; KCT = 34;
        bias = b1; cs = c1;
        hop = h1p + (size_t)(1 - (t & 1)) * HPS;
    } else {                           // ---- layer 2, step t = s-1 ----
        const int t = s - 1; if (t < 0) return;
        As0 = h1p + (size_t)(1 - (t & 1)) * HPS; KC0 = 32;  // h1(t)
        As1 = h2p + (size_t)(t & 1) * HPS;                  // h2(t-1)
        Pk = P2; KCB = 64; KCT = 64;
        bias = b2; cs = c2;
        hop = h2p + (size_t)(1 - (t & 1)) * HPS;
    }

    const int tid = threadIdx.x;
    const int w   = tid >> 6;          // 0..7
    const int l   = tid & 63;
    const int q   = l >> 4;
    const int c16 = l & 15;
    const int mh  = w & 1;             // 64-row half
    const int kp  = w >> 1;            // K quarter (0..3)

    const int m0  = (tile >> 5) * 128;
    const int n0  = (tile & 31) * 32;
    const int mG0 = (m0 >> 4) + mh * 4;    // wave's first A granule (of 4)

    const size_t l8 = (size_t)l * 8;

    const _Float16* bp[4][2];          // per-(gate, nf-half) packed-B granule base
#pragma unroll
    for (int g = 0; g < 4; ++g)
#pragma unroll
        for (int nf = 0; nf < 2; ++nf)
            bp[g][nf] = Pk + ((size_t)(g * 64 + (n0 >> 4) + nf) * KCB) * 512 + l8;

    float4v acc[4][4][2] = {};         // [gate][msub][nf] = 32 frags (128 AGPR)

    auto loadS = [&](int kc, FragSet& S) {
        const _Float16* ab; size_t astr;
        if (kc < KC0) { ab = As0 + (size_t)kc * 512;         astr = (size_t)KC0 * 512; }
        else          { ab = As1 + (size_t)(kc - KC0) * 512; astr = 32ull * 512; }
        ab += (size_t)mG0 * astr + l8;
#pragma unroll
        for (int ms = 0; ms < 4; ++ms)
            S.A[ms] = *(const half8*)(ab + (size_t)ms * astr);
#pragma unroll
        for (int g = 0; g < 4; ++g)
#pragma unroll
            for (int nf = 0; nf < 2; ++nf)
                S.B[g][nf] = *(const half8*)(bp[g][nf] + (size_t)kc * 512);
    };
    auto computeS = [&](const FragSet& S) {
        __builtin_amdgcn_s_setprio(1);             // T5: favor MFMA wave
#pragma unroll
        for (int g = 0; g < 4; ++g)
#pragma unroll
            for (int ms = 0; ms < 4; ++ms)
#pragma unroll
                for (int nf = 0; nf < 2; ++nf)
                    acc[g][ms][nf] = __builtin_amdgcn_mfma_f32_16x16x32_f16(
                        S.A[ms], S.B[g][nf], acc[g][ms][nf], 0, 0, 0);
        __builtin_amdgcn_s_setprio(0);
    };

    // ---- K loop over this wave's quarter (TLP hides load latency) ----
    const int base = KCT >> 2;                 // 8 (l1) / 16 (l2)
    const int rem  = KCT & 3;                  // 2 (l1) / 0 (l2)
    const int len  = base + (kp < rem ? 1 : 0);
    const int kcS  = kp * base + (kp < rem ? kp : rem);

    FragSet S;
#pragma unroll 2
    for (int kc = kcS; kc < kcS + len; ++kc) {
        loadS(kc, S);
        computeS(S);
    }

    // ---- 2-round cross-wave K reduction via 128 KB LDS ----
    __shared__ float4v red[8][16][64];         // [writer wave][frag][lane]
    // Round 1: exchange nf halves with partner w^2 (kp bit0 flip).
    if ((kp & 1) == 0) {
#pragma unroll
        for (int g = 0; g < 4; ++g)
#pragma unroll
            for (int ms = 0; ms < 4; ++ms)
                red[w][g * 4 + ms][l] = acc[g][ms][1];
    } else {
#pragma unroll
        for (int g = 0; g < 4; ++g)
#pragma unroll
            for (int ms = 0; ms < 4; ++ms)
                red[w][g * 4 + ms][l] = acc[g][ms][0];
    }
    __syncthreads();
    float4v acc1[4][4];                // owned nf, summed over K half
    if ((kp & 1) == 0) {
#pragma unroll
        for (int g = 0; g < 4; ++g)
#pragma unroll
            for (int ms = 0; ms < 4; ++ms)
                acc1[g][ms] = acc[g][ms][0] + red[w ^ 2][g * 4 + ms][l];
    } else {
#pragma unroll
        for (int g = 0; g < 4; ++g)
#pragma unroll
            for (int ms = 0; ms < 4; ++ms)
                acc1[g][ms] = acc[g][ms][1] + red[w ^ 2][g * 4 + ms][l];
    }
    __syncthreads();                   // WAR: buffer reused in round 2
    // Round 2: exchange ms pairs with partner w^4 (kp bit1 flip).
    if ((kp >> 1) == 0) {
#pragma unroll
        for (int g = 0; g < 4; ++g)
#pragma unroll
            for (int j = 0; j < 2; ++j)
                red[w][g * 2 + j][l] = acc1[g][2 + j];
    } else {
#pragma unroll
        for (int g = 0; g < 4; ++g)
#pragma unroll
            for (int j = 0; j < 2; ++j)
                red[w][g * 2 + j][l] = acc1[g][j];
    }
    __syncthreads();
    float4v out[4][2];                 // full sums for owned (nf, ms-pair)
    if ((kp >> 1) == 0) {
#pragma unroll
        for (int g = 0; g < 4; ++g)
#pragma unroll
            for (int j = 0; j < 2; ++j)
                out[g][j] = acc1[g][j] + red[w ^ 4][g * 2 + j][l];
    } else {
#pragma unroll
        for (int g = 0; g < 4; ++g)
#pragma unroll
            for (int j = 0; j < 2; ++j)
                out[g][j] = acc1[g][2 + j] + red[w ^ 4][g * 2 + j][l];
    }

    // ---- fused gate epilogue; h written in A-granule layout ----
    // Wave owns rows [m0+mh*64+own_msp*32, +32) x units [n0+own_nf*16, +16).
    const int own_nf  = kp & 1;
    const int own_msp = kp >> 1;
    const int ng = n0 + own_nf * 16 + c16;
    const float bi  = bias[ng];
    const float bff = bias[1024 + ng];
    const float bg  = bias[2048 + ng];
    const float bo  = bias[3072 + ng];
    const int kcH   = n0 >> 5;
    const int laneW = (own_nf * 2 + (c16 >> 3)) << 4;
    const int jW    = c16 & 7;
#pragma unroll
    for (int j = 0; j < 2; ++j) {
        const int msg = own_msp * 2 + j;
        const int mG  = mG0 + msg;
        _Float16* hg = hop + ((size_t)(mG * 32 + kcH)) * 512 + (size_t)laneW * 8 + jW;
#pragma unroll
        for (int i = 0; i < 4; ++i) {
            const int m = m0 + mh * 64 + msg * 16 + q * 4 + i;
            const float zi = out[0][j][i] + bi;
            const float zf = out[1][j][i] + bff;
            const float zg = out[2][j][i] + bg;
            const float zo = out[3][j][i] + bo;
            const float ig = sigf(zi);
            const float fg = sigf(zf);
            const float gg = tanhfast(zg);
            const float og = sigf(zo);
            const size_t cidx = (size_t)m * 1024 + ng;
            const float cc = fg * cs[cidx] + ig * gg;
            cs[cidx] = cc;
            hg[(q * 4 + i) * 8] = (_Float16)(og * tanhfast(cc));
        }
    }
}

// ---------------------------------------------------------------------------
// Pack [W (KA,4096) | U (K-KA,4096)] fp32 row-major into B-fragment granules.
// ---------------------------------------------------------------------------
__global__ void pack_weights(const float* __restrict__ W, const float* __restrict__ U,
                             int KA, int KC, _Float16* __restrict__ out)
{
    const size_t e = (size_t)blockIdx.x * blockDim.x + threadIdx.x;
    const size_t total = (size_t)256 * KC * 512;
    if (e >= total) return;
    const int j    = (int)(e & 7);
    const int lane = (int)((e >> 3) & 63);
    const size_t g = e >> 9;
    const int kc  = (int)(g % KC);
    const int ntG = (int)(g / KC);
    const int col = ntG * 16 + (lane & 15);
    const int k   = kc * 32 + (lane >> 4) * 8 + j;
    const float v = (k < KA) ? W[(size_t)k * 4096 + col]
                             : U[(size_t)(k - KA) * 4096 + col];
    out[e] = (_Float16)v;
}

// ---------------------------------------------------------------------------
// Pack x (B=512, T=128, F=64) fp32 into per-timestep A-granules.
// ---------------------------------------------------------------------------
__global__ void pack_x(const float* __restrict__ x, _Float16* __restrict__ xp)
{
    const int e = blockIdx.x * blockDim.x + threadIdx.x;
    if (e >= 512 * 128 * 64) return;
    const int j  = e & 7;
    const int l  = (e >> 3) & 63;
    const int g  = e >> 9;
    const int kc = g & 1;
    const int tm = g >> 1;
    const int mG = tm & 31;
    const int t  = tm >> 5;
    const int m  = mG * 16 + (l & 15);
    const int f  = kc * 32 + (l >> 4) * 8 + j;
    xp[e] = (_Float16)x[((size_t)m * 128 + t) * 64 + f];
}

// ---------------------------------------------------------------------------
// Dense head on packed h2: out[m] = sigmoid(h2[m,:].Wd + bd).
// ---------------------------------------------------------------------------
__global__ __launch_bounds__(64) void dense_head(const _Float16* __restrict__ h2p,
                                                 const float* __restrict__ Wd,
                                                 const float* __restrict__ bd,
                                                 float* __restrict__ out)
{
    const int mG = blockIdx.x;
    const int l  = threadIdx.x;
    float s = 0.0f;
    for (int kc = 0; kc < 32; ++kc) {
        half8 f = *(const half8*)(h2p + ((size_t)(mG * 32 + kc)) * 512 + (size_t)l * 8);
        const int kb = kc * 32 + (l >> 4) * 8;
#pragma unroll
        for (int j = 0; j < 8; ++j) s += (float)f[j] * Wd[kb + j];
    }
    s += __shfl_xor(s, 16);
    s += __shfl_xor(s, 32);
    if (l < 16) out[mG * 16 + l] = 1.0f / (1.0f + __expf(-(s + bd[0])));
}

// ---------------------------------------------------------------------------

extern "C" void kernel_launch(void* const* d_in, const int* in_sizes, int n_in,
                              void* d_out, int out_size, void* d_ws, size_t ws_size,
                              hipStream_t stream)
{
    const float* x  = (const float*)d_in[0];
    const float* W1 = (const float*)d_in[1];
    const float* U1 = (const float*)d_in[2];
    const float* b1 = (const float*)d_in[3];
    const float* W2 = (const float*)d_in[4];
    const float* U2 = (const float*)d_in[5];
    const float* b2 = (const float*)d_in[6];
    const float* Wd = (const float*)d_in[7];
    const float* bd = (const float*)d_in[8];
    float* out = (float*)d_out;

    char* ws = (char*)d_ws;
    size_t off = 0;
    auto alloc = [&](size_t bytes) {
        char* p = ws + off;
        off = (off + bytes + 255) & ~(size_t)255;
        return p;
    };
    _Float16* xp  = (_Float16*)alloc(512ull * 128 * 64 * 2);  // packed x
    _Float16* P1  = (_Float16*)alloc(256ull * 34 * 512 * 2);  // packed layer1 W|U
    _Float16* P2  = (_Float16*)alloc(256ull * 64 * 512 * 2);  // packed layer2 W|U
    _Float16* h1p = (_Float16*)alloc(2ull * HPS * 2);         // packed h1 ping-pong
    _Float16* h2p = (_Float16*)alloc(2ull * HPS * 2);         // packed h2 ping-pong
    float*    c1  = (float*)alloc(512ull * 1024 * 4);
    float*    c2  = (float*)alloc(512ull * 1024 * 4);

    // zero initial state (ws is re-poisoned to 0xAA before every launch)
    hipMemsetAsync(c1, 0, 512ull * 1024 * 4, stream);
    hipMemsetAsync(c2, 0, 512ull * 1024 * 4, stream);
    hipMemsetAsync(h1p, 0, HPS * 2, stream);   // slot 0 (read at t=0)
    hipMemsetAsync(h2p, 0, HPS * 2, stream);   // slot 0

    pack_x<<<(512 * 128 * 64 + 255) / 256, 256, 0, stream>>>(x, xp);
    pack_weights<<<(256 * 34 * 512 + 255) / 256, 256, 0, stream>>>(W1, U1, 64, 34, P1);
    pack_weights<<<(256 * 64 * 512 + 255) / 256, 256, 0, stream>>>(W2, U2, 1024, 64, P2);

    // 129 pipelined launches: launch s does layer1(s) + layer2(s-1)
    for (int s = 0; s <= 128; ++s) {
        fused_step<<<256, 512, 0, stream>>>(s, xp, P1, P2,
                                            b1, c1, h1p, b2, c2, h2p);
    }
    // h2(127) lands in slot 0
    dense_head<<<32, 64, 0, stream>>>(h2p, Wd, bd, out);
}